// Round 1
// baseline (139.083 us; speedup 1.0000x reference)
//
#include <hip/hip_runtime.h>

namespace {

constexpr int B = 4, LX = 512, LM = 512, D = 256;
// Fold 2*log2(e) into the projection so tanh(z) = 1 - 2*rcp(1 + exp2(KSCALE*z))
constexpr float KSCALE = 2.8853900817779268f;

// ---------------------------------------------------------------------------
// proj_kernel: computes both projections, scaled by KSCALE.
//   z==0: o1[r][e] = (sum_d x[r][d]*W1[e][d] + b1[e]) * KSCALE    (r in [0,2048))
//   z==1: o2[r][e] = (sum_d mem[r][d]*W2[e][d])       * KSCALE
// 64x64 output tile per block, 256 threads, 4x4 per thread, k-chunks of 32.
// ---------------------------------------------------------------------------
__global__ __launch_bounds__(256) void proj_kernel(
    const float* __restrict__ x, const float* __restrict__ mem,
    const float* __restrict__ W1, const float* __restrict__ b1,
    const float* __restrict__ W2, float* __restrict__ o1, float* __restrict__ o2)
{
    const int tid = threadIdx.x;
    const int z = blockIdx.z;
    const float* __restrict__ A = z ? mem : x;
    const float* __restrict__ W = z ? W2 : W1;
    float* __restrict__ O = z ? o2 : o1;
    const int r0 = blockIdx.y * 64;
    const int e0 = blockIdx.x * 64;

    __shared__ float As[32][64]; // [k][row]
    __shared__ float Ws[32][64]; // [k][col]

    const int tx = tid & 15, ty = tid >> 4;
    const int sr = tid & 63;         // staging row/col (0..63)
    const int sk = (tid >> 6) * 8;   // staging k base (0,8,16,24)

    float acc[4][4];
#pragma unroll
    for (int i = 0; i < 4; ++i)
#pragma unroll
        for (int j = 0; j < 4; ++j) acc[i][j] = 0.f;

    for (int kc = 0; kc < D; kc += 32) {
        float4 a0 = *(const float4*)&A[(r0 + sr) * D + kc + sk];
        float4 a1 = *(const float4*)&A[(r0 + sr) * D + kc + sk + 4];
        float4 w0 = *(const float4*)&W[(e0 + sr) * D + kc + sk];
        float4 w1 = *(const float4*)&W[(e0 + sr) * D + kc + sk + 4];
        __syncthreads();
        As[sk + 0][sr] = a0.x; As[sk + 1][sr] = a0.y;
        As[sk + 2][sr] = a0.z; As[sk + 3][sr] = a0.w;
        As[sk + 4][sr] = a1.x; As[sk + 5][sr] = a1.y;
        As[sk + 6][sr] = a1.z; As[sk + 7][sr] = a1.w;
        Ws[sk + 0][sr] = w0.x; Ws[sk + 1][sr] = w0.y;
        Ws[sk + 2][sr] = w0.z; Ws[sk + 3][sr] = w0.w;
        Ws[sk + 4][sr] = w1.x; Ws[sk + 5][sr] = w1.y;
        Ws[sk + 6][sr] = w1.z; Ws[sk + 7][sr] = w1.w;
        __syncthreads();
#pragma unroll 4
        for (int k = 0; k < 32; ++k) {
            float4 av = *(const float4*)&As[k][ty * 4];
            float4 wv = *(const float4*)&Ws[k][tx * 4];
            float a[4] = {av.x, av.y, av.z, av.w};
            float w[4] = {wv.x, wv.y, wv.z, wv.w};
#pragma unroll
            for (int i = 0; i < 4; ++i)
#pragma unroll
                for (int j = 0; j < 4; ++j)
                    acc[i][j] = fmaf(a[i], w[j], acc[i][j]);
        }
    }

    float bb[4] = {0.f, 0.f, 0.f, 0.f};
    if (z == 0) {
        float4 bv = *(const float4*)&b1[e0 + tx * 4];
        bb[0] = bv.x; bb[1] = bv.y; bb[2] = bv.z; bb[3] = bv.w;
    }
#pragma unroll
    for (int i = 0; i < 4; ++i) {
        const int r = r0 + ty * 4 + i;
        float4 o;
        o.x = (acc[i][0] + bb[0]) * KSCALE;
        o.y = (acc[i][1] + bb[1]) * KSCALE;
        o.z = (acc[i][2] + bb[2]) * KSCALE;
        o.w = (acc[i][3] + bb[3]) * KSCALE;
        *(float4*)&O[r * D + e0 + tx * 4] = o;
    }
}

// ---------------------------------------------------------------------------
// tanh_score_kernel: S[b,x,m] = sum_d tanh-term, with mask.
//   Using tanh(z) = 1 - 2*r, r = rcp(1 + exp2(z')) where z' = i1'+i2' (pre-scaled).
//   S = sumWt - 2 * sum_d r_d * Wt[d].
// 32x32 (x,m) tile / block, 256 threads, 2x2 per thread (strided), D chunk 128.
// LDS stride 132: 16B-aligned for b128, bank-stagger 4 -> <=2-way (free).
// ---------------------------------------------------------------------------
__global__ __launch_bounds__(256) void tanh_score_kernel(
    const float* __restrict__ i1p, const float* __restrict__ i2p,
    const float* __restrict__ Wt, const int* __restrict__ mask,
    float* __restrict__ out)
{
    const int tid = threadIdx.x;
    const int b = blockIdx.z;
    const int x0 = blockIdx.y * 32;
    const int m0 = blockIdx.x * 32;

    __shared__ float sA[32][132];
    __shared__ float sB[32][132];
    __shared__ float sW[256];
    sW[tid] = Wt[tid];

    const int tx = tid & 15, ty = tid >> 4;
    const int srow = tid >> 3;        // 0..31
    const int sc = (tid & 7) * 16;    // 0..112

    float acc00 = 0.f, acc01 = 0.f, acc10 = 0.f, acc11 = 0.f, accW = 0.f;

    for (int c = 0; c < 2; ++c) {
        const int dB = c * 128;
        const float* gA = &i1p[(b * LX + x0 + srow) * D + dB + sc];
        const float* gB = &i2p[(b * LM + m0 + srow) * D + dB + sc];
        float4 A0 = *(const float4*)(gA + 0);
        float4 A1 = *(const float4*)(gA + 4);
        float4 A2 = *(const float4*)(gA + 8);
        float4 A3 = *(const float4*)(gA + 12);
        float4 B0 = *(const float4*)(gB + 0);
        float4 B1 = *(const float4*)(gB + 4);
        float4 B2 = *(const float4*)(gB + 8);
        float4 B3 = *(const float4*)(gB + 12);
        __syncthreads(); // protect previous chunk's readers before overwrite
        *(float4*)&sA[srow][sc + 0]  = A0;
        *(float4*)&sA[srow][sc + 4]  = A1;
        *(float4*)&sA[srow][sc + 8]  = A2;
        *(float4*)&sA[srow][sc + 12] = A3;
        *(float4*)&sB[srow][sc + 0]  = B0;
        *(float4*)&sB[srow][sc + 4]  = B1;
        *(float4*)&sB[srow][sc + 8]  = B2;
        *(float4*)&sB[srow][sc + 12] = B3;
        __syncthreads();

#pragma unroll 2
        for (int d = 0; d < 128; d += 4) {
            float4 wv  = *(const float4*)&sW[dB + d];
            float4 ra0 = *(const float4*)&sA[ty][d];
            float4 ra1 = *(const float4*)&sA[ty + 16][d];
            float4 rb0 = *(const float4*)&sB[tx][d];
            float4 rb1 = *(const float4*)&sB[tx + 16][d];
            accW += wv.x + wv.y + wv.z + wv.w;

#define TERM(a, bb) __builtin_amdgcn_rcpf(1.0f + __builtin_amdgcn_exp2f((a) + (bb)))
            acc00 = fmaf(TERM(ra0.x, rb0.x), wv.x, acc00);
            acc01 = fmaf(TERM(ra0.x, rb1.x), wv.x, acc01);
            acc10 = fmaf(TERM(ra1.x, rb0.x), wv.x, acc10);
            acc11 = fmaf(TERM(ra1.x, rb1.x), wv.x, acc11);

            acc00 = fmaf(TERM(ra0.y, rb0.y), wv.y, acc00);
            acc01 = fmaf(TERM(ra0.y, rb1.y), wv.y, acc01);
            acc10 = fmaf(TERM(ra1.y, rb0.y), wv.y, acc10);
            acc11 = fmaf(TERM(ra1.y, rb1.y), wv.y, acc11);

            acc00 = fmaf(TERM(ra0.z, rb0.z), wv.z, acc00);
            acc01 = fmaf(TERM(ra0.z, rb1.z), wv.z, acc01);
            acc10 = fmaf(TERM(ra1.z, rb0.z), wv.z, acc10);
            acc11 = fmaf(TERM(ra1.z, rb1.z), wv.z, acc11);

            acc00 = fmaf(TERM(ra0.w, rb0.w), wv.w, acc00);
            acc01 = fmaf(TERM(ra0.w, rb1.w), wv.w, acc01);
            acc10 = fmaf(TERM(ra1.w, rb0.w), wv.w, acc10);
            acc11 = fmaf(TERM(ra1.w, rb1.w), wv.w, acc11);
#undef TERM
        }
    }

    // S = sum(Wt) - 2*acc ; apply mask; write.
    const int mA = m0 + tx, mB = m0 + tx + 16;
    const int xA = x0 + ty, xB = x0 + ty + 16;
    const bool k0 = mask[b * LM + mA] != 0;
    const bool k1 = mask[b * LM + mB] != 0;
    const float s00 = accW - 2.f * acc00;
    const float s01 = accW - 2.f * acc01;
    const float s10 = accW - 2.f * acc10;
    const float s11 = accW - 2.f * acc11;
    out[((size_t)b * LX + xA) * LM + mA] = k0 ? s00 : -10000.f;
    out[((size_t)b * LX + xA) * LM + mB] = k1 ? s01 : -10000.f;
    out[((size_t)b * LX + xB) * LM + mA] = k0 ? s10 : -10000.f;
    out[((size_t)b * LX + xB) * LM + mB] = k1 ? s11 : -10000.f;
}

} // namespace

extern "C" void kernel_launch(void* const* d_in, const int* in_sizes, int n_in,
                              void* d_out, int out_size, void* d_ws, size_t ws_size,
                              hipStream_t stream)
{
    const float* x    = (const float*)d_in[0];
    const float* mem  = (const float*)d_in[1];
    const int*   mask = (const int*)d_in[2];
    const float* W1   = (const float*)d_in[3];
    const float* b1   = (const float*)d_in[4];
    const float* W2   = (const float*)d_in[5];
    const float* Wt   = (const float*)d_in[6];
    float* out = (float*)d_out;

    float* i1p = (float*)d_ws;             // (B*LX, D) scaled item1
    float* i2p = i1p + (size_t)B * LX * D; // (B*LM, D) scaled item2

    // Both projections in one launch: grid.z selects {item1,item2}.
    proj_kernel<<<dim3(D / 64, (B * LX) / 64, 2), 256, 0, stream>>>(
        x, mem, W1, b1, W2, i1p, i2p);

    tanh_score_kernel<<<dim3(LM / 32, LX / 32, B), 256, 0, stream>>>(
        i1p, i2p, Wt, mask, out);
}

// Round 2
// 112.710 us; speedup vs baseline: 1.2340x; 1.2340x over previous
//
#include <hip/hip_runtime.h>

namespace {

constexpr int B = 4, LX = 512, LM = 512, D = 256;
// Fold 2*log2(e) into the projection: tanh(u) = 1 - 2/(1+exp2(KSCALE*u))
constexpr float KSCALE = 2.8853900817779268f;
constexpr float CLAMP = 15.0f; // exp2 arg clamp: E<=2^15, A<=2^30, den<=2^120 (finite)

typedef __attribute__((ext_vector_type(8))) short short8;
typedef __attribute__((ext_vector_type(4))) float f32x4;

__device__ __forceinline__ short f2bf_rne(float f) {
    unsigned u = __float_as_uint(f);
    u += 0x7FFFu + ((u >> 16) & 1u);
    return (short)(u >> 16);
}

// ---------------------------------------------------------------------------
// proj_mfma: E1[r][e] = exp2(clamp(KSCALE*(x@W1^T + b1)))   (r in [0,2048))
//            E2[r][e] = exp2(clamp(KSCALE*(mem@W2^T)))
// One 16x16 tile per wave, k=256 in 8 MFMA steps, no LDS. Both operands are
// row-major k-contiguous = exact A/B fragment layout (m/n = lane&15,
// k = (lane>>4)*8 + j). 4096 wave-tiles -> 1024 blocks (4/CU).
// ---------------------------------------------------------------------------
__global__ __launch_bounds__(256) void proj_mfma(
    const float* __restrict__ x, const float* __restrict__ mem,
    const float* __restrict__ W1, const float* __restrict__ b1,
    const float* __restrict__ W2, float* __restrict__ E1, float* __restrict__ E2)
{
    const int tid  = threadIdx.x;
    const int wv   = tid >> 6;
    const int lane = tid & 63;
    const int tile = blockIdx.x * 4 + wv;
    const int z    = tile >> 11;          // 0: x/W1, 1: mem/W2
    const int t    = tile & 2047;
    const int r0   = (t >> 4) << 4;       // 128 row-tiles
    const int e0   = (t & 15) << 4;       // 16 e-tiles
    const int lr   = lane & 15;
    const int quad = lane >> 4;

    const float* __restrict__ A = (z ? mem : x) + (size_t)(r0 + lr) * D + quad * 8;
    const float* __restrict__ W = (z ? W2 : W1) + (size_t)(e0 + lr) * D + quad * 8;

    f32x4 acc = {0.f, 0.f, 0.f, 0.f};
#pragma unroll
    for (int kc = 0; kc < D; kc += 32) {
        float4 a0 = *(const float4*)(A + kc);
        float4 a1 = *(const float4*)(A + kc + 4);
        float4 w0 = *(const float4*)(W + kc);
        float4 w1 = *(const float4*)(W + kc + 4);
        short8 af, bf;
        af[0] = f2bf_rne(a0.x); af[1] = f2bf_rne(a0.y);
        af[2] = f2bf_rne(a0.z); af[3] = f2bf_rne(a0.w);
        af[4] = f2bf_rne(a1.x); af[5] = f2bf_rne(a1.y);
        af[6] = f2bf_rne(a1.z); af[7] = f2bf_rne(a1.w);
        bf[0] = f2bf_rne(w0.x); bf[1] = f2bf_rne(w0.y);
        bf[2] = f2bf_rne(w0.z); bf[3] = f2bf_rne(w0.w);
        bf[4] = f2bf_rne(w1.x); bf[5] = f2bf_rne(w1.y);
        bf[6] = f2bf_rne(w1.z); bf[7] = f2bf_rne(w1.w);
        acc = __builtin_amdgcn_mfma_f32_16x16x32_bf16(af, bf, acc, 0, 0, 0);
    }

    float* __restrict__ E = z ? E2 : E1;
    const float bias = z ? 0.f : b1[e0 + lr];
#pragma unroll
    for (int reg = 0; reg < 4; ++reg) {
        const int row = quad * 4 + reg;   // C/D: col=lane&15, row=quad*4+reg
        float arg = KSCALE * (acc[reg] + bias);
        arg = fminf(fmaxf(arg, -CLAMP), CLAMP);
        E[(size_t)(r0 + row) * D + e0 + lr] = __builtin_amdgcn_exp2f(arg);
    }
}

// ---------------------------------------------------------------------------
// tanh_score: S[b,x,m] = sumWt - 2 * sum_d Wt[d] / (1 + E1[x,d]*E2[m,d]), mask.
// 4 d-terms share one rcp via common denominator (clamp makes den finite).
// 32x32 (x,m) tile, 256 threads, 2x2/thread strided, D chunks of 128 in LDS.
// Wt read via uniform (scalar) loads from global — no LDS for it.
// ---------------------------------------------------------------------------
__global__ __launch_bounds__(256) void tanh_score_kernel(
    const float* __restrict__ e1p, const float* __restrict__ e2p,
    const float* __restrict__ Wt, const int* __restrict__ mask,
    float* __restrict__ out)
{
    const int tid = threadIdx.x;
    const int b = blockIdx.z;
    const int x0 = blockIdx.y * 32;
    const int m0 = blockIdx.x * 32;

    __shared__ float sA[32][132];
    __shared__ float sB[32][132];

    const int tx = tid & 15, ty = tid >> 4;
    const int srow = tid >> 3;        // 0..31
    const int sc = (tid & 7) * 16;    // 0..112

    float acc00 = 0.f, acc01 = 0.f, acc10 = 0.f, acc11 = 0.f, accW = 0.f;

    for (int c = 0; c < 2; ++c) {
        const int dB = c * 128;
        const float* gA = &e1p[((size_t)b * LX + x0 + srow) * D + dB + sc];
        const float* gB = &e2p[((size_t)b * LM + m0 + srow) * D + dB + sc];
        float4 A0 = *(const float4*)(gA + 0);
        float4 A1 = *(const float4*)(gA + 4);
        float4 A2 = *(const float4*)(gA + 8);
        float4 A3 = *(const float4*)(gA + 12);
        float4 B0 = *(const float4*)(gB + 0);
        float4 B1 = *(const float4*)(gB + 4);
        float4 B2 = *(const float4*)(gB + 8);
        float4 B3 = *(const float4*)(gB + 12);
        __syncthreads();
        *(float4*)&sA[srow][sc + 0]  = A0;
        *(float4*)&sA[srow][sc + 4]  = A1;
        *(float4*)&sA[srow][sc + 8]  = A2;
        *(float4*)&sA[srow][sc + 12] = A3;
        *(float4*)&sB[srow][sc + 0]  = B0;
        *(float4*)&sB[srow][sc + 4]  = B1;
        *(float4*)&sB[srow][sc + 8]  = B2;
        *(float4*)&sB[srow][sc + 12] = B3;
        __syncthreads();

#pragma unroll 4
        for (int d = 0; d < 128; d += 4) {
            const float4 wq  = *(const float4*)&Wt[dB + d]; // uniform -> s_load
            const float4 ra0 = *(const float4*)&sA[ty][d];
            const float4 ra1 = *(const float4*)&sA[ty + 16][d];
            const float4 rb0 = *(const float4*)&sB[tx][d];
            const float4 rb1 = *(const float4*)&sB[tx + 16][d];
            accW += (wq.x + wq.y) + (wq.z + wq.w);

            // 4-term common-denominator: sum_i w_i/(1+A_i), one rcp.
#define QUAD(ra, rb, accv) {                                           \
            const float A0 = fmaf((ra).x, (rb).x, 1.f);                \
            const float A1 = fmaf((ra).y, (rb).y, 1.f);                \
            const float A2 = fmaf((ra).z, (rb).z, 1.f);                \
            const float A3 = fmaf((ra).w, (rb).w, 1.f);                \
            const float L = A0 * A1, R = A2 * A3;                      \
            const float den = L * R;                                   \
            const float t0 = fmaf(wq.y, A0, wq.x * A1);                \
            const float t1 = fmaf(wq.w, A2, wq.z * A3);                \
            const float N = fmaf(t1, L, t0 * R);                       \
            (accv) = fmaf(N, __builtin_amdgcn_rcpf(den), (accv)); }

            QUAD(ra0, rb0, acc00);
            QUAD(ra0, rb1, acc01);
            QUAD(ra1, rb0, acc10);
            QUAD(ra1, rb1, acc11);
#undef QUAD
        }
    }

    const int mA = m0 + tx, mB = m0 + tx + 16;
    const int xA = x0 + ty, xB = x0 + ty + 16;
    const bool k0 = mask[b * LM + mA] != 0;
    const bool k1 = mask[b * LM + mB] != 0;
    const float s00 = accW - 2.f * acc00;
    const float s01 = accW - 2.f * acc01;
    const float s10 = accW - 2.f * acc10;
    const float s11 = accW - 2.f * acc11;
    out[((size_t)b * LX + xA) * LM + mA] = k0 ? s00 : -10000.f;
    out[((size_t)b * LX + xA) * LM + mB] = k1 ? s01 : -10000.f;
    out[((size_t)b * LX + xB) * LM + mA] = k0 ? s10 : -10000.f;
    out[((size_t)b * LX + xB) * LM + mB] = k1 ? s11 : -10000.f;
}

} // namespace

extern "C" void kernel_launch(void* const* d_in, const int* in_sizes, int n_in,
                              void* d_out, int out_size, void* d_ws, size_t ws_size,
                              hipStream_t stream)
{
    const float* x    = (const float*)d_in[0];
    const float* mem  = (const float*)d_in[1];
    const int*   mask = (const int*)d_in[2];
    const float* W1   = (const float*)d_in[3];
    const float* b1   = (const float*)d_in[4];
    const float* W2   = (const float*)d_in[5];
    const float* Wt   = (const float*)d_in[6];
    float* out = (float*)d_out;

    float* E1 = (float*)d_ws;             // (B*LX, D) exp2-transformed item1
    float* E2 = E1 + (size_t)B * LX * D;  // (B*LM, D) exp2-transformed item2

    proj_mfma<<<dim3(1024), 256, 0, stream>>>(x, mem, W1, b1, W2, E1, E2);

    tanh_score_kernel<<<dim3(LM / 32, LX / 32, B), 256, 0, stream>>>(
        E1, E2, Wt, mask, out);
}

// Round 3
// 104.841 us; speedup vs baseline: 1.3266x; 1.0751x over previous
//
#include <hip/hip_runtime.h>

namespace {

constexpr int B = 4, LX = 512, LM = 512, D = 256;
// Fold 2*log2(e) into the projection: tanh(u) = 1 - 2/(1+exp2(KSCALE*u))
constexpr float KSCALE = 2.8853900817779268f;
constexpr float CLAMP = 15.0f; // E in [2^-15,2^15] -> den <= 2^120 finite

typedef __attribute__((ext_vector_type(8))) short short8;
typedef __attribute__((ext_vector_type(4))) float f32x4;

__device__ __forceinline__ unsigned bfbits(float f) {
    unsigned u = __float_as_uint(f);
    u += 0x7FFFu + ((u >> 16) & 1u);
    return u >> 16;
}
__device__ __forceinline__ int pack2(float a, float b) {
    return (int)(bfbits(a) | (bfbits(b) << 16));
}

// ---------------------------------------------------------------------------
// proj_mfma v2: combined GEMM, M=4096 (rows 0..2047 = x@W1^T + b1,
// rows 2048..4095 = mem@W2^T), N=256, K=256. Output E = exp2(clamp(KSCALE*y)).
// 32x64 tile/block, 256 thr (4 waves); wave (g,cg) covers 16 rows x 32 cols.
// Coalesced float4 global loads -> bf16 LDS (stride 40 shorts = 80 B,
// 16B-aligned rows) -> ds_read_b128 fragments -> mfma_f32_16x16x32_bf16.
// Grid (128,4) = 512 blocks = 2/CU.
// ---------------------------------------------------------------------------
__global__ __launch_bounds__(256) void proj_mfma(
    const float* __restrict__ x, const float* __restrict__ mem,
    const float* __restrict__ W1, const float* __restrict__ b1v,
    const float* __restrict__ W2, float* __restrict__ E1, float* __restrict__ E2)
{
    const int tid = threadIdx.x;
    const int m0c = blockIdx.x * 32;     // combined row base
    const int e0  = blockIdx.y * 64;     // col base
    const int z   = m0c >= 2048;
    const int r0  = z ? (m0c - 2048) : m0c;
    const float* __restrict__ A = (z ? mem : x) + (size_t)r0 * D;
    const float* __restrict__ W = z ? W2 : W1;
    float* __restrict__ E = z ? E2 : E1;

    __shared__ short sA[32][40];
    __shared__ short sW[64][40];

    const int wv = tid >> 6, lane = tid & 63;
    const int lr = lane & 15, quad = lane >> 4;
    const int g   = wv & 1;              // row-group (16 rows)
    const int cg0 = (wv >> 1) * 2;       // col-groups cg0, cg0+1

    const int srA = tid >> 3;            // 0..31
    const int scA = (tid & 7) * 4;       // float offset 0..28

    f32x4 acc0 = {0.f, 0.f, 0.f, 0.f};
    f32x4 acc1 = {0.f, 0.f, 0.f, 0.f};

    for (int kc = 0; kc < D; kc += 32) {
        float4 av = *(const float4*)&A[(size_t)srA * D + kc + scA];
        float4 w0 = *(const float4*)&W[(size_t)(e0 + srA) * D + kc + scA];
        float4 w1 = *(const float4*)&W[(size_t)(e0 + 32 + srA) * D + kc + scA];
        __syncthreads();
        *(int2*)&sA[srA][scA]      = make_int2(pack2(av.x, av.y), pack2(av.z, av.w));
        *(int2*)&sW[srA][scA]      = make_int2(pack2(w0.x, w0.y), pack2(w0.z, w0.w));
        *(int2*)&sW[srA + 32][scA] = make_int2(pack2(w1.x, w1.y), pack2(w1.z, w1.w));
        __syncthreads();
        short8 af  = *(const short8*)&sA[g * 16 + lr][quad * 8];
        short8 bf0 = *(const short8*)&sW[cg0 * 16 + lr][quad * 8];
        short8 bf1 = *(const short8*)&sW[cg0 * 16 + 16 + lr][quad * 8];
        acc0 = __builtin_amdgcn_mfma_f32_16x16x32_bf16(af, bf0, acc0, 0, 0, 0);
        acc1 = __builtin_amdgcn_mfma_f32_16x16x32_bf16(af, bf1, acc1, 0, 0, 0);
    }

    const float bias0 = z ? 0.f : b1v[e0 + cg0 * 16 + lr];
    const float bias1 = z ? 0.f : b1v[e0 + cg0 * 16 + 16 + lr];
#pragma unroll
    for (int reg = 0; reg < 4; ++reg) {
        const int row = r0 + g * 16 + quad * 4 + reg; // C/D: row=quad*4+reg
        float a0 = KSCALE * (acc0[reg] + bias0);
        float a1 = KSCALE * (acc1[reg] + bias1);
        a0 = fminf(fmaxf(a0, -CLAMP), CLAMP);
        a1 = fminf(fmaxf(a1, -CLAMP), CLAMP);
        E[(size_t)row * D + e0 + cg0 * 16 + lr]      = __builtin_amdgcn_exp2f(a0);
        E[(size_t)row * D + e0 + cg0 * 16 + 16 + lr] = __builtin_amdgcn_exp2f(a1);
    }
}

// ---------------------------------------------------------------------------
// tanh_score v2: S = sumWt - 2*sum_d Wt[d]/(1+E1[x,d]E2[m,d]), mask.
// 32(x) x 64(m) tile, 256 thr, 2x4/thread (strided), D-chunks of 64.
// LDS stride 68 floats: 16B-aligned, read aliasing <=2-way (free).
// 6 ds_read_b128 feed 8 common-denominator QUADs (1 rcp per 4 d-terms).
// Grid (8,16,4) = 512 blocks = 2/CU.
// ---------------------------------------------------------------------------
__global__ __launch_bounds__(256) void tanh_score_kernel(
    const float* __restrict__ e1p, const float* __restrict__ e2p,
    const float* __restrict__ Wt, const int* __restrict__ mask,
    float* __restrict__ out)
{
    const int tid = threadIdx.x;
    const int b  = blockIdx.z;
    const int x0 = blockIdx.y * 32;
    const int m0 = blockIdx.x * 64;

    __shared__ float sA[32][68];
    __shared__ float sB[64][68];

    const int tx = tid & 15, ty = tid >> 4;
    const int rA = tid >> 3, cA = (tid & 7) * 8;   // sA staging: 32 rows x 8 floats
    const int rB = tid >> 2, cB = (tid & 3) * 16;  // sB staging: 64 rows x 16 floats

    float a00 = 0.f, a01 = 0.f, a02 = 0.f, a03 = 0.f;
    float a10 = 0.f, a11 = 0.f, a12 = 0.f, a13 = 0.f;
    float accW = 0.f;

    for (int c = 0; c < 4; ++c) {
        const int dB = c * 64;
        const float* gA = &e1p[((size_t)b * LX + x0 + rA) * D + dB + cA];
        const float* gB = &e2p[((size_t)b * LM + m0 + rB) * D + dB + cB];
        float4 A0 = *(const float4*)(gA + 0);
        float4 A1 = *(const float4*)(gA + 4);
        float4 B0 = *(const float4*)(gB + 0);
        float4 B1 = *(const float4*)(gB + 4);
        float4 B2 = *(const float4*)(gB + 8);
        float4 B3 = *(const float4*)(gB + 12);
        __syncthreads();
        *(float4*)&sA[rA][cA + 0] = A0;
        *(float4*)&sA[rA][cA + 4] = A1;
        *(float4*)&sB[rB][cB + 0]  = B0;
        *(float4*)&sB[rB][cB + 4]  = B1;
        *(float4*)&sB[rB][cB + 8]  = B2;
        *(float4*)&sB[rB][cB + 12] = B3;
        __syncthreads();

#pragma unroll 4
        for (int d = 0; d < 64; d += 4) {
            const float4 wq  = *(const float4*)&Wt[dB + d]; // uniform -> s_load
            const float4 ra0 = *(const float4*)&sA[ty][d];
            const float4 ra1 = *(const float4*)&sA[ty + 16][d];
            const float4 rb0 = *(const float4*)&sB[tx][d];
            const float4 rb1 = *(const float4*)&sB[tx + 16][d];
            const float4 rb2 = *(const float4*)&sB[tx + 32][d];
            const float4 rb3 = *(const float4*)&sB[tx + 48][d];
            accW += (wq.x + wq.y) + (wq.z + wq.w);

#define QUAD(ra, rb, accv) {                                           \
            const float A0_ = fmaf((ra).x, (rb).x, 1.f);               \
            const float A1_ = fmaf((ra).y, (rb).y, 1.f);               \
            const float A2_ = fmaf((ra).z, (rb).z, 1.f);               \
            const float A3_ = fmaf((ra).w, (rb).w, 1.f);               \
            const float L_ = A0_ * A1_, R_ = A2_ * A3_;                \
            const float den_ = L_ * R_;                                \
            const float t0_ = fmaf(wq.y, A0_, wq.x * A1_);             \
            const float t1_ = fmaf(wq.w, A2_, wq.z * A3_);             \
            const float N_ = fmaf(t1_, L_, t0_ * R_);                  \
            (accv) = fmaf(N_, __builtin_amdgcn_rcpf(den_), (accv)); }

            QUAD(ra0, rb0, a00); QUAD(ra0, rb1, a01);
            QUAD(ra0, rb2, a02); QUAD(ra0, rb3, a03);
            QUAD(ra1, rb0, a10); QUAD(ra1, rb1, a11);
            QUAD(ra1, rb2, a12); QUAD(ra1, rb3, a13);
#undef QUAD
        }
    }

    const int xA = x0 + ty, xB = x0 + ty + 16;
    const int mm[4] = {m0 + tx, m0 + tx + 16, m0 + tx + 32, m0 + tx + 48};
    float s0[4] = {accW - 2.f * a00, accW - 2.f * a01,
                   accW - 2.f * a02, accW - 2.f * a03};
    float s1[4] = {accW - 2.f * a10, accW - 2.f * a11,
                   accW - 2.f * a12, accW - 2.f * a13};
#pragma unroll
    for (int k = 0; k < 4; ++k) {
        const bool keep = mask[b * LM + mm[k]] != 0;
        out[((size_t)b * LX + xA) * LM + mm[k]] = keep ? s0[k] : -10000.f;
        out[((size_t)b * LX + xB) * LM + mm[k]] = keep ? s1[k] : -10000.f;
    }
}

} // namespace

extern "C" void kernel_launch(void* const* d_in, const int* in_sizes, int n_in,
                              void* d_out, int out_size, void* d_ws, size_t ws_size,
                              hipStream_t stream)
{
    const float* x    = (const float*)d_in[0];
    const float* mem  = (const float*)d_in[1];
    const int*   mask = (const int*)d_in[2];
    const float* W1   = (const float*)d_in[3];
    const float* b1   = (const float*)d_in[4];
    const float* W2   = (const float*)d_in[5];
    const float* Wt   = (const float*)d_in[6];
    float* out = (float*)d_out;

    float* E1 = (float*)d_ws;             // (B*LX, D) exp2-transformed item1
    float* E2 = E1 + (size_t)B * LX * D;  // (B*LM, D) exp2-transformed item2

    proj_mfma<<<dim3(128, 4), 256, 0, stream>>>(x, mem, W1, b1, W2, E1, E2);

    tanh_score_kernel<<<dim3(LM / 64, LX / 32, B), 256, 0, stream>>>(
        E1, E2, Wt, mask, out);
}